// Round 2
// baseline (8693.697 us; speedup 1.0000x reference)
//
#include <hip/hip_runtime.h>
#include <math.h>

#define BB 16
#define LL 128
#define HH 1024
#define EE 512
#define VV 32000
#define G3 3072
#define NBLK 256

__device__ __forceinline__ float sigmoidf_(float x){ return 1.0f/(1.0f+expf(-x)); }

// Build row index: enc row r = (l,b) -> token = input[b*L + l]
__global__ void k_rowidx(const int* __restrict__ inp, int* __restrict__ idx){
  int r = blockIdx.x*256 + threadIdx.x;
  if (r < 2048){ int l = r >> 4, b = r & 15; idx[r] = inp[b*LL + l]; }
}

// Generic tiled GEMM: C[r][c] = act(bias[c] + sum_k A[row(r)][k]*Bm[k][c])
template<int ACT, int KK>
__global__ __launch_bounds__(256) void k_gemm(const float* __restrict__ A, const int* __restrict__ rowidx,
                       const float* __restrict__ Bm, const float* __restrict__ bias,
                       float* __restrict__ C, int N){
  constexpr int KS = (KK==512)?9:10;
  __shared__ float As[32*KK];
  const int tid = threadIdx.x;
  const int r0 = blockIdx.x*32;
  const int c  = blockIdx.y*512 + (tid<<1);
  for (int i = tid; i < 32*KK; i += 256){
    int rr = i >> KS;
    int row = r0 + rr;
    int arow = rowidx ? rowidx[row] : row;
    int kk = i - (rr<<KS);
    As[i] = A[(size_t)arow*KK + kk];
  }
  __syncthreads();
  float2 acc[32];
  #pragma unroll
  for (int r=0;r<32;r++){ acc[r].x=0.f; acc[r].y=0.f; }
  for (int k=0;k<KK;k++){
    const float2 w = *(const float2*)(Bm + (size_t)k*N + c);
    #pragma unroll
    for (int r=0;r<32;r++){
      float a = As[(r<<KS)+k];
      acc[r].x = fmaf(a,w.x,acc[r].x);
      acc[r].y = fmaf(a,w.y,acc[r].y);
    }
  }
  const float2 bv = *(const float2*)(bias + c);
  #pragma unroll
  for (int r=0;r<32;r++){
    float x = acc[r].x + bv.x, y = acc[r].y + bv.y;
    if (ACT==1){ x = tanhf(x); y = tanhf(y); }
    *(float2*)(C + (size_t)(r0+r)*N + c) = make_float2(x,y);
  }
}

// gx0[j] = bih0[j] + sum_k emb[SOS=1][k] * Wih0[k][j]
__global__ void k_gx0(const float* __restrict__ emb, const float* __restrict__ Wih0,
                      const float* __restrict__ bih0, float* __restrict__ gx0){
  int j = blockIdx.x*256 + threadIdx.x;
  float acc = bih0[j];
  const float* e = emb + EE;  // row of SOS index 1
  for (int k=0;k<EE;k++) acc = fmaf(e[k], Wih0[(size_t)k*G3 + j], acc);
  gx0[j] = acc;
}

// Persistent GRU chain: all 128 steps in one launch, weights held in registers.
// 256 blocks (block = 4 hidden j), 256 threads: tid = jl*64 + lane,
// lane = bh*32 + kh. Thread covers k in [kh*32,kh*32+32), b in [bh*8,bh*8+8),
// gates r/z/n of column j = blockIdx.x*4 + jl.  W regs: 96/thread.
__global__ __launch_bounds__(256,1) void k_chain_persist(
    const float* Hinit, float* Hall, const float* __restrict__ W,
    const float* __restrict__ gxbase, int gx_sstride, int gx_bstride,
    const float* __restrict__ bhh, int* bar)
{
  __shared__ float part[192][33];
  __shared__ float red[192];
  const int tid  = threadIdx.x;
  const int jl   = tid >> 6;
  const int lane = tid & 63;
  const int kh   = lane & 31;
  const int bh   = lane >> 5;
  const int jb   = blockIdx.x << 2;
  const int j    = jb + jl;
  const int k0   = kh << 5;
  const int b0   = bh << 3;
  int* cnt = bar;
  int* gen = bar + 1;

  // Load this thread's weight slice once (reused for all 128 steps).
  float w0[32], w1[32], w2[32];
  #pragma unroll
  for (int i=0;i<32;i++){
    const float* wr = W + (size_t)(k0+i)*G3 + j;
    w0[i] = wr[0]; w1[i] = wr[1024]; w2[i] = wr[2048];
  }

  for (int s=0; s<LL; s++){
    const float* hp = (s==0) ? Hinit : (Hall + (size_t)(s-1)*(BB*HH));
    float a0[8], a1[8], a2[8];
    #pragma unroll
    for (int b=0;b<8;b++){ a0[b]=0.f; a1[b]=0.f; a2[b]=0.f; }
    #pragma unroll
    for (int b=0;b<8;b++){
      const float4* hr = (const float4*)(hp + (size_t)(b0+b)*HH + k0);
      float hbuf[32];
      #pragma unroll
      for (int q=0;q<8;q++){
        float4 v = hr[q];
        hbuf[q*4+0]=v.x; hbuf[q*4+1]=v.y; hbuf[q*4+2]=v.z; hbuf[q*4+3]=v.w;
      }
      #pragma unroll
      for (int i=0;i<32;i++){
        a0[b] = fmaf(w0[i], hbuf[i], a0[b]);
        a1[b] = fmaf(w1[i], hbuf[i], a1[b]);
        a2[b] = fmaf(w2[i], hbuf[i], a2[b]);
      }
    }
    // cross-lane (kh) reduction via LDS
    const int rbase = (jl*2 + bh)*24;
    #pragma unroll
    for (int b=0;b<8;b++){
      part[rbase + b     ][kh] = a0[b];
      part[rbase + 8 + b ][kh] = a1[b];
      part[rbase + 16 + b][kh] = a2[b];
    }
    __syncthreads();
    if (tid < 192){
      float ssum = 0.f;
      #pragma unroll
      for (int i=0;i<32;i++) ssum += part[tid][i];
      red[tid] = ssum;
    }
    __syncthreads();
    if (tid < 64){
      const int b  = tid & 15;
      const int j2 = tid >> 4;
      const int jj = jb + j2;
      const int row = (j2*2 + (b>>3))*24 + (b&7);
      const float* gx = gxbase + (size_t)s*gx_sstride + (size_t)b*gx_bstride;
      float ghr = red[row     ] + bhh[jj];
      float ghz = red[row + 8 ] + bhh[1024+jj];
      float ghn = red[row + 16] + bhh[2048+jj];
      float r = sigmoidf_(gx[jj]      + ghr);
      float z = sigmoidf_(gx[1024+jj] + ghz);
      float n = tanhf    (gx[2048+jj] + r*ghn);
      float hprev = hp[b*HH + jj];
      Hall[(size_t)s*(BB*HH) + b*HH + jj] = (1.f-z)*n + z*hprev;
    }
    // grid-wide barrier (device-scope atomics; sense = gen snapshot)
    __syncthreads();
    if (s < LL-1){
      if (tid==0){
        __threadfence();  // release my h-writes
        int g = __hip_atomic_load(gen, __ATOMIC_RELAXED, __HIP_MEMORY_SCOPE_AGENT);
        if (__hip_atomic_fetch_add(cnt, 1, __ATOMIC_ACQ_REL, __HIP_MEMORY_SCOPE_AGENT) == NBLK-1){
          __hip_atomic_store(cnt, 0, __ATOMIC_RELAXED, __HIP_MEMORY_SCOPE_AGENT);
          __hip_atomic_fetch_add(gen, 1, __ATOMIC_ACQ_REL, __HIP_MEMORY_SCOPE_AGENT);
        } else {
          while (__hip_atomic_load(gen, __ATOMIC_RELAXED, __HIP_MEMORY_SCOPE_AGENT) == g)
            __builtin_amdgcn_s_sleep(2);
        }
        __threadfence();  // acquire others' h-writes
      }
      __syncthreads();
    }
  }
}

// Batched attention: per block (s_chunk of 8, b): scores -> softmax -> ctx
__global__ __launch_bounds__(256) void k_attn(const float* __restrict__ enc, const float* __restrict__ H1,
                       float* __restrict__ ctx){
  __shared__ float h1s[8][HH];
  __shared__ float sc[8][LL];
  __shared__ float part[2][8][LL];
  const int tid = threadIdx.x;
  const int s0 = blockIdx.x*8, b = blockIdx.y;
  for (int i = tid; i < 8*HH; i += 256){
    int si = i >> 10, k = i & 1023;
    h1s[si][k] = H1[(size_t)(s0+si)*BB*HH + (size_t)b*HH + k];
  }
  __syncthreads();
  {
    const int l = tid & 127, half = tid >> 7;
    const float4* er = (const float4*)(enc + ((size_t)l*BB + b)*HH + half*512);
    float a[8];
    #pragma unroll
    for (int s=0;s<8;s++) a[s]=0.f;
    for (int q=0;q<128;q++){
      float4 e = er[q];
      #pragma unroll
      for (int s=0;s<8;s++){
        const float4 h = *(const float4*)(&h1s[s][half*512 + q*4]);
        a[s] += h.x*e.x + h.y*e.y + h.z*e.z + h.w*e.w;
      }
    }
    #pragma unroll
    for (int s=0;s<8;s++) part[half][s][l] = a[s];
  }
  __syncthreads();
  for (int p = tid; p < 1024; p += 256){
    int s = p >> 7, l = p & 127;
    sc[s][l] = (part[0][s][l] + part[1][s][l]) * 0.03125f;   // 1/sqrt(1024)
  }
  __syncthreads();
  {
    int s = tid >> 5, lid = tid & 31;
    float v0 = sc[s][lid], v1 = sc[s][lid+32], v2 = sc[s][lid+64], v3 = sc[s][lid+96];
    float m = fmaxf(fmaxf(v0,v1),fmaxf(v2,v3));
    for (int off=16; off>=1; off>>=1) m = fmaxf(m, __shfl_xor(m, off, 32));
    float e0=__expf(v0-m), e1=__expf(v1-m), e2=__expf(v2-m), e3=__expf(v3-m);
    float ssum = e0+e1+e2+e3;
    for (int off=16; off>=1; off>>=1) ssum += __shfl_xor(ssum, off, 32);
    float inv = 1.0f/ssum;
    sc[s][lid]=e0*inv; sc[s][lid+32]=e1*inv; sc[s][lid+64]=e2*inv; sc[s][lid+96]=e3*inv;
  }
  __syncthreads();
  {
    float acc[4][8];
    #pragma unroll
    for (int q=0;q<4;q++)
      #pragma unroll
      for (int s=0;s<8;s++) acc[q][s]=0.f;
    for (int l=0;l<128;l++){
      const float* er = enc + ((size_t)l*BB + b)*HH + tid;
      float a[8];
      #pragma unroll
      for (int s=0;s<8;s++) a[s] = sc[s][l];
      #pragma unroll
      for (int q=0;q<4;q++){
        float e = er[q*256];
        #pragma unroll
        for (int s=0;s<8;s++) acc[q][s] = fmaf(a[s], e, acc[q][s]);
      }
    }
    #pragma unroll
    for (int s=0;s<8;s++)
      #pragma unroll
      for (int q=0;q<4;q++)
        ctx[(size_t)(s0+s)*BB*HH + (size_t)b*HH + tid + q*256] = acc[q][s];
  }
}

// Gathered logits + sigmoid + BCE: one block per (b,t)
__global__ __launch_bounds__(256) void k_logit(const float* __restrict__ H1, const float* __restrict__ ctx,
                        const float* __restrict__ Wout, const float* __restrict__ bout,
                        const int* __restrict__ inp, const int* __restrict__ ts,
                        float* __restrict__ outp, float* __restrict__ bce){
  __shared__ float rbuf[256];
  const int i = blockIdx.x;
  const int b = i >> 7, t = i & 127;
  const int v = inp[b*LL + t];
  const int tid = threadIdx.x;
  const float* h1r = H1 + ((size_t)t*BB + b)*HH;
  const float* cxr = ctx + ((size_t)t*BB + b)*HH;
  float acc = 0.f;
  #pragma unroll
  for (int q=0;q<4;q++){
    int k = tid + q*256;
    acc = fmaf(h1r[k], Wout[(size_t)k*VV + v], acc);
  }
  #pragma unroll
  for (int q=0;q<4;q++){
    int k = tid + q*256;
    acc = fmaf(cxr[k], Wout[(size_t)(k+1024)*VV + v], acc);
  }
  rbuf[tid] = acc;
  __syncthreads();
  for (int s=128; s>0; s>>=1){
    if (tid < s) rbuf[tid] += rbuf[tid+s];
    __syncthreads();
  }
  if (tid==0){
    float logit = rbuf[0] + bout[v];
    float p = 1.0f/(1.0f + expf(-logit));
    outp[b*LL + t] = p;
    float pc = fminf(fmaxf(p, 1e-12f), 1.0f - 1e-7f);
    float tg = (float)ts[0];
    bce[i] = -(tg*logf(pc) + (1.0f-tg)*log1pf(-pc));
  }
}

__global__ void k_loss(const float* __restrict__ bce, float* __restrict__ out0){
  __shared__ float rbuf[256];
  int tid = threadIdx.x;
  float s = 0.f;
  for (int i = tid; i < 2048; i += 256) s += bce[i];
  rbuf[tid] = s; __syncthreads();
  for (int st=128; st>0; st>>=1){
    if (tid<st) rbuf[tid]+=rbuf[tid+st];
    __syncthreads();
  }
  if (tid==0) out0[0] = rbuf[0] * (1.0f/(2048.0f*16.0f));
}

extern "C" void kernel_launch(void* const* d_in, const int* in_sizes, int n_in,
                              void* d_out, int out_size, void* d_ws, size_t ws_size,
                              hipStream_t stream){
  (void)in_sizes; (void)n_in; (void)out_size; (void)ws_size;
  const int*   inp   = (const int*)d_in[0];
  const int*   ts    = (const int*)d_in[2];
  const float* emb   = (const float*)d_in[3];
  const float* encW  = (const float*)d_in[4];
  const float* encb  = (const float*)d_in[5];
  const float* Wih0  = (const float*)d_in[6];
  const float* Whh0  = (const float*)d_in[7];
  const float* bih0  = (const float*)d_in[8];
  const float* bhh0  = (const float*)d_in[9];
  const float* Wih1  = (const float*)d_in[10];
  const float* Whh1  = (const float*)d_in[11];
  const float* bih1  = (const float*)d_in[12];
  const float* bhh1  = (const float*)d_in[13];
  const float* Wout  = (const float*)d_in[14];
  const float* bout  = (const float*)d_in[15];
  float* out = (float*)d_out;

  float* ws      = (float*)d_ws;
  float* enc_out = ws;                         // [128][16][1024]
  float* H0      = enc_out + 2097152;          // [128][16][1024]
  float* H1      = H0 + 2097152;               // [128][16][1024]
  float* GX1     = H1 + 2097152;               // [128][16][3072]
  float* CTX     = GX1 + 6291456;              // [128][16][1024]
  float* gx0     = CTX + 2097152;              // [3072]
  float* bceb    = gx0 + 3072;                 // [2048]
  int*   rowidx  = (int*)(bceb + 2048);        // [2048]
  int*   bar     = rowidx + 2048;              // [2] cnt, gen

  hipMemsetAsync(bar, 0, 2*sizeof(int), stream);
  k_rowidx<<<8,256,0,stream>>>(inp, rowidx);
  // Encoder: enc_out[l][b][:] = tanh(emb[token] @ encW + encb)
  k_gemm<1,512><<<dim3(64,2),256,0,stream>>>(emb, rowidx, encW, encb, enc_out, HH);
  k_gx0<<<12,256,0,stream>>>(emb, Wih0, bih0, gx0);

  const float* enclast = enc_out + (size_t)127*BB*HH;  // h_init

  // Chain 0: persistent kernel, 128 steps internally
  k_chain_persist<<<NBLK,256,0,stream>>>(enclast, H0, Whh0, gx0, 0, 0, bhh0, bar);
  // Batched GX1 = H0_all @ Wih1 + bih1
  k_gemm<0,1024><<<dim3(64,6),256,0,stream>>>(H0, nullptr, Wih1, bih1, GX1, G3);
  // Chain 1: persistent kernel
  k_chain_persist<<<NBLK,256,0,stream>>>(enclast, H1, Whh1, GX1, BB*G3, G3, bhh1, bar);
  // Batched attention
  k_attn<<<dim3(16,16),256,0,stream>>>(enc_out, H1, CTX);
  // Gathered logits + sigmoid + bce; then loss reduction
  k_logit<<<2048,256,0,stream>>>(H1, CTX, Wout, bout, inp, ts, out+1, bceb);
  k_loss<<<1,256,0,stream>>>(bceb, out);
}

// Round 3
// 8047.445 us; speedup vs baseline: 1.0803x; 1.0803x over previous
//
#include <hip/hip_runtime.h>
#include <math.h>

#define BB 16
#define LL 128
#define HH 1024
#define EE 512
#define VV 32000
#define G3 3072
#define NBLK 256

__device__ __forceinline__ float sigmoidf_(float x){ return 1.0f/(1.0f+expf(-x)); }

__global__ void k_rowidx(const int* __restrict__ inp, int* __restrict__ idx){
  int r = blockIdx.x*256 + threadIdx.x;
  if (r < 2048){ int l = r >> 4, b = r & 15; idx[r] = inp[b*LL + l]; }
}

template<int ACT, int KK>
__global__ __launch_bounds__(256) void k_gemm(const float* __restrict__ A, const int* __restrict__ rowidx,
                       const float* __restrict__ Bm, const float* __restrict__ bias,
                       float* __restrict__ C, int N){
  constexpr int KS = (KK==512)?9:10;
  __shared__ float As[32*KK];
  const int tid = threadIdx.x;
  const int r0 = blockIdx.x*32;
  const int c  = blockIdx.y*512 + (tid<<1);
  for (int i = tid; i < 32*KK; i += 256){
    int rr = i >> KS;
    int row = r0 + rr;
    int arow = rowidx ? rowidx[row] : row;
    int kk = i - (rr<<KS);
    As[i] = A[(size_t)arow*KK + kk];
  }
  __syncthreads();
  float2 acc[32];
  #pragma unroll
  for (int r=0;r<32;r++){ acc[r].x=0.f; acc[r].y=0.f; }
  for (int k=0;k<KK;k++){
    const float2 w = *(const float2*)(Bm + (size_t)k*N + c);
    #pragma unroll
    for (int r=0;r<32;r++){
      float a = As[(r<<KS)+k];
      acc[r].x = fmaf(a,w.x,acc[r].x);
      acc[r].y = fmaf(a,w.y,acc[r].y);
    }
  }
  const float2 bv = *(const float2*)(bias + c);
  #pragma unroll
  for (int r=0;r<32;r++){
    float x = acc[r].x + bv.x, y = acc[r].y + bv.y;
    if (ACT==1){ x = tanhf(x); y = tanhf(y); }
    *(float2*)(C + (size_t)(r0+r)*N + c) = make_float2(x,y);
  }
}

__global__ void k_gx0(const float* __restrict__ emb, const float* __restrict__ Wih0,
                      const float* __restrict__ bih0, float* __restrict__ gx0){
  int j = blockIdx.x*256 + threadIdx.x;
  float acc = bih0[j];
  const float* e = emb + EE;
  for (int k=0;k<EE;k++) acc = fmaf(e[k], Wih0[(size_t)k*G3 + j], acc);
  gx0[j] = acc;
}

// Persistent GRU chain: weights in LDS (un-sinkable), coalesced h loads,
// intra-wave shuffle k-reduction, grid sense-barrier between steps.
__global__ __launch_bounds__(256,1) void k_chain_persist(
    const float* Hinit, float* Hall, const float* __restrict__ W,
    const float* __restrict__ gxbase, int gx_sstride, int gx_bstride,
    const float* __restrict__ bhh, int* bar)
{
  __shared__ float wl[12][1024];
  const int tid = threadIdx.x;
  const int kc  = tid & 63;
  const int bc  = tid >> 6;
  const int jb  = blockIdx.x << 2;
  const int b0  = bc << 2;
  int* cnt = bar; int* gen = bar + 1;

  for (int i = tid; i < 3072; i += 256){
    int g = i >> 10, k = i & 1023;
    const float4 w4 = *(const float4*)(W + (size_t)k*G3 + g*1024 + jb);
    wl[g*4+0][k] = w4.x; wl[g*4+1][k] = w4.y; wl[g*4+2][k] = w4.z; wl[g*4+3][k] = w4.w;
  }
  __syncthreads();

  const int jl = kc & 3, bi_p = kc >> 2;
  const int jp = jb + jl, bp = b0 + bi_p;
  float br = 0.f, bz = 0.f, bn = 0.f;
  if (kc < 16){ br = bhh[jp]; bz = bhh[1024+jp]; bn = bhh[2048+jp]; }

  for (int s = 0; s < LL; s++){
    const float* hp = (s==0) ? Hinit : (Hall + (size_t)(s-1)*(BB*HH));
    float4 h4[4][4];
    #pragma unroll
    for (int bi=0; bi<4; bi++)
      #pragma unroll
      for (int q=0; q<4; q++)
        h4[bi][q] = *(const float4*)(hp + (size_t)(b0+bi)*HH + q*256 + (kc<<2));

    float acc[12][4];
    #pragma unroll
    for (int c=0;c<12;c++)
      #pragma unroll
      for (int bi=0;bi<4;bi++) acc[c][bi] = 0.f;

    #pragma unroll
    for (int c=0;c<12;c++){
      const float4* wc = (const float4*)(&wl[c][0]);
      float4 wA = wc[kc];
      float4 wB = wc[64 + kc];
      float4 wC = wc[128 + kc];
      float4 wD = wc[192 + kc];
      #pragma unroll
      for (int bi=0; bi<4; bi++){
        float v = acc[c][bi];
        v = fmaf(wA.x, h4[bi][0].x, v); v = fmaf(wA.y, h4[bi][0].y, v);
        v = fmaf(wA.z, h4[bi][0].z, v); v = fmaf(wA.w, h4[bi][0].w, v);
        v = fmaf(wB.x, h4[bi][1].x, v); v = fmaf(wB.y, h4[bi][1].y, v);
        v = fmaf(wB.z, h4[bi][1].z, v); v = fmaf(wB.w, h4[bi][1].w, v);
        v = fmaf(wC.x, h4[bi][2].x, v); v = fmaf(wC.y, h4[bi][2].y, v);
        v = fmaf(wC.z, h4[bi][2].z, v); v = fmaf(wC.w, h4[bi][2].w, v);
        v = fmaf(wD.x, h4[bi][3].x, v); v = fmaf(wD.y, h4[bi][3].y, v);
        v = fmaf(wD.z, h4[bi][3].z, v); v = fmaf(wD.w, h4[bi][3].w, v);
        acc[c][bi] = v;
      }
    }

    #pragma unroll
    for (int c=0;c<12;c++)
      #pragma unroll
      for (int bi=0;bi<4;bi++){
        float v = acc[c][bi];
        v += __shfl_xor(v, 1,  64);
        v += __shfl_xor(v, 2,  64);
        v += __shfl_xor(v, 4,  64);
        v += __shfl_xor(v, 8,  64);
        v += __shfl_xor(v, 16, 64);
        v += __shfl_xor(v, 32, 64);
        acc[c][bi] = v;
      }

    if (kc < 16){
      float ghr = 0.f, ghz = 0.f, ghn = 0.f;
      #pragma unroll
      for (int c=0;c<4;c++)
        #pragma unroll
        for (int bi=0;bi<4;bi++){
          bool sel = (jl==c) & (bi_p==bi);
          ghr = sel ? acc[c][bi]   : ghr;
          ghz = sel ? acc[4+c][bi] : ghz;
          ghn = sel ? acc[8+c][bi] : ghn;
        }
      const float* gx = gxbase + (size_t)s*gx_sstride + (size_t)bp*gx_bstride;
      float r = sigmoidf_(gx[jp]      + ghr + br);
      float z = sigmoidf_(gx[1024+jp] + ghz + bz);
      float n = tanhf    (gx[2048+jp] + r*(ghn + bn));
      float hprev = hp[(size_t)bp*HH + jp];
      Hall[(size_t)s*(BB*HH) + (size_t)bp*HH + jp] = (1.f-z)*n + z*hprev;
    }

    if (s < LL-1){
      __syncthreads();
      if (tid==0){
        __threadfence();
        int g = __hip_atomic_load(gen, __ATOMIC_RELAXED, __HIP_MEMORY_SCOPE_AGENT);
        if (__hip_atomic_fetch_add(cnt, 1, __ATOMIC_ACQ_REL, __HIP_MEMORY_SCOPE_AGENT) == NBLK-1){
          __hip_atomic_store(cnt, 0, __ATOMIC_RELAXED, __HIP_MEMORY_SCOPE_AGENT);
          __hip_atomic_fetch_add(gen, 1, __ATOMIC_ACQ_REL, __HIP_MEMORY_SCOPE_AGENT);
        } else {
          while (__hip_atomic_load(gen, __ATOMIC_RELAXED, __HIP_MEMORY_SCOPE_AGENT) == g)
            __builtin_amdgcn_s_sleep(1);
        }
        __threadfence();
      }
      __syncthreads();
    }
  }
}

__global__ __launch_bounds__(256) void k_attn(const float* __restrict__ enc, const float* __restrict__ H1,
                       float* __restrict__ ctx){
  __shared__ float h1s[8][HH];
  __shared__ float sc[8][LL];
  __shared__ float part[2][8][LL];
  const int tid = threadIdx.x;
  const int s0 = blockIdx.x*8, b = blockIdx.y;
  for (int i = tid; i < 8*HH; i += 256){
    int si = i >> 10, k = i & 1023;
    h1s[si][k] = H1[(size_t)(s0+si)*BB*HH + (size_t)b*HH + k];
  }
  __syncthreads();
  {
    const int l = tid & 127, half = tid >> 7;
    const float4* er = (const float4*)(enc + ((size_t)l*BB + b)*HH + half*512);
    float a[8];
    #pragma unroll
    for (int s=0;s<8;s++) a[s]=0.f;
    for (int q=0;q<128;q++){
      float4 e = er[q];
      #pragma unroll
      for (int s=0;s<8;s++){
        const float4 h = *(const float4*)(&h1s[s][half*512 + q*4]);
        a[s] += h.x*e.x + h.y*e.y + h.z*e.z + h.w*e.w;
      }
    }
    #pragma unroll
    for (int s=0;s<8;s++) part[half][s][l] = a[s];
  }
  __syncthreads();
  for (int p = tid; p < 1024; p += 256){
    int s = p >> 7, l = p & 127;
    sc[s][l] = (part[0][s][l] + part[1][s][l]) * 0.03125f;
  }
  __syncthreads();
  {
    int s = tid >> 5, lid = tid & 31;
    float v0 = sc[s][lid], v1 = sc[s][lid+32], v2 = sc[s][lid+64], v3 = sc[s][lid+96];
    float m = fmaxf(fmaxf(v0,v1),fmaxf(v2,v3));
    for (int off=16; off>=1; off>>=1) m = fmaxf(m, __shfl_xor(m, off, 32));
    float e0=__expf(v0-m), e1=__expf(v1-m), e2=__expf(v2-m), e3=__expf(v3-m);
    float ssum = e0+e1+e2+e3;
    for (int off=16; off>=1; off>>=1) ssum += __shfl_xor(ssum, off, 32);
    float inv = 1.0f/ssum;
    sc[s][lid]=e0*inv; sc[s][lid+32]=e1*inv; sc[s][lid+64]=e2*inv; sc[s][lid+96]=e3*inv;
  }
  __syncthreads();
  {
    float acc[4][8];
    #pragma unroll
    for (int q=0;q<4;q++)
      #pragma unroll
      for (int s=0;s<8;s++) acc[q][s]=0.f;
    for (int l=0;l<128;l++){
      const float* er = enc + ((size_t)l*BB + b)*HH + tid;
      float a[8];
      #pragma unroll
      for (int s=0;s<8;s++) a[s] = sc[s][l];
      #pragma unroll
      for (int q=0;q<4;q++){
        float e = er[q*256];
        #pragma unroll
        for (int s=0;s<8;s++) acc[q][s] = fmaf(a[s], e, acc[q][s]);
      }
    }
    #pragma unroll
    for (int s=0;s<8;s++)
      #pragma unroll
      for (int q=0;q<4;q++)
        ctx[(size_t)(s0+s)*BB*HH + (size_t)b*HH + tid + q*256] = acc[q][s];
  }
}

__global__ __launch_bounds__(256) void k_logit(const float* __restrict__ H1, const float* __restrict__ ctx,
                        const float* __restrict__ Wout, const float* __restrict__ bout,
                        const int* __restrict__ inp, const int* __restrict__ ts,
                        float* __restrict__ outp, float* __restrict__ bce){
  __shared__ float rbuf[256];
  const int i = blockIdx.x;
  const int b = i >> 7, t = i & 127;
  const int v = inp[b*LL + t];
  const int tid = threadIdx.x;
  const float* h1r = H1 + ((size_t)t*BB + b)*HH;
  const float* cxr = ctx + ((size_t)t*BB + b)*HH;
  float acc = 0.f;
  #pragma unroll
  for (int q=0;q<4;q++){
    int k = tid + q*256;
    acc = fmaf(h1r[k], Wout[(size_t)k*VV + v], acc);
  }
  #pragma unroll
  for (int q=0;q<4;q++){
    int k = tid + q*256;
    acc = fmaf(cxr[k], Wout[(size_t)(k+1024)*VV + v], acc);
  }
  rbuf[tid] = acc;
  __syncthreads();
  for (int s=128; s>0; s>>=1){
    if (tid < s) rbuf[tid] += rbuf[tid+s];
    __syncthreads();
  }
  if (tid==0){
    float logit = rbuf[0] + bout[v];
    float p = 1.0f/(1.0f + expf(-logit));
    outp[b*LL + t] = p;
    float pc = fminf(fmaxf(p, 1e-12f), 1.0f - 1e-7f);
    float tg = (float)ts[0];
    bce[i] = -(tg*logf(pc) + (1.0f-tg)*log1pf(-pc));
  }
}

__global__ void k_loss(const float* __restrict__ bce, float* __restrict__ out0){
  __shared__ float rbuf[256];
  int tid = threadIdx.x;
  float s = 0.f;
  for (int i = tid; i < 2048; i += 256) s += bce[i];
  rbuf[tid] = s; __syncthreads();
  for (int st=128; st>0; st>>=1){
    if (tid<st) rbuf[tid]+=rbuf[tid+st];
    __syncthreads();
  }
  if (tid==0) out0[0] = rbuf[0] * (1.0f/(2048.0f*16.0f));
}

extern "C" void kernel_launch(void* const* d_in, const int* in_sizes, int n_in,
                              void* d_out, int out_size, void* d_ws, size_t ws_size,
                              hipStream_t stream){
  (void)in_sizes; (void)n_in; (void)out_size; (void)ws_size;
  const int*   inp   = (const int*)d_in[0];
  const int*   ts    = (const int*)d_in[2];
  const float* emb   = (const float*)d_in[3];
  const float* encW  = (const float*)d_in[4];
  const float* encb  = (const float*)d_in[5];
  const float* Whh0  = (const float*)d_in[7];
  const float* Wih0  = (const float*)d_in[6];
  const float* bih0  = (const float*)d_in[8];
  const float* bhh0  = (const float*)d_in[9];
  const float* Wih1  = (const float*)d_in[10];
  const float* Whh1  = (const float*)d_in[11];
  const float* bih1  = (const float*)d_in[12];
  const float* bhh1  = (const float*)d_in[13];
  const float* Wout  = (const float*)d_in[14];
  const float* bout  = (const float*)d_in[15];
  float* out = (float*)d_out;

  float* ws      = (float*)d_ws;
  float* enc_out = ws;
  float* H0      = enc_out + 2097152;
  float* H1      = H0 + 2097152;
  float* GX1     = H1 + 2097152;
  float* CTX     = GX1 + 6291456;
  float* gx0     = CTX + 2097152;
  float* bceb    = gx0 + 3072;
  int*   rowidx  = (int*)(bceb + 2048);
  int*   bar     = rowidx + 2048;

  hipMemsetAsync(bar, 0, 2*sizeof(int), stream);
  k_rowidx<<<8,256,0,stream>>>(inp, rowidx);
  k_gemm<1,512><<<dim3(64,2),256,0,stream>>>(emb, rowidx, encW, encb, enc_out, HH);
  k_gx0<<<12,256,0,stream>>>(emb, Wih0, bih0, gx0);

  const float* enclast = enc_out + (size_t)127*BB*HH;

  k_chain_persist<<<NBLK,256,0,stream>>>(enclast, H0, Whh0, gx0, 0, 0, bhh0, bar);
  k_gemm<0,1024><<<dim3(64,6),256,0,stream>>>(H0, nullptr, Wih1, bih1, GX1, G3);
  k_chain_persist<<<NBLK,256,0,stream>>>(enclast, H1, Whh1, GX1, BB*G3, G3, bhh1, bar);
  k_attn<<<dim3(16,16),256,0,stream>>>(enc_out, H1, CTX);
  k_logit<<<2048,256,0,stream>>>(H1, CTX, Wout, bout, inp, ts, out+1, bceb);
  k_loss<<<1,256,0,stream>>>(bceb, out);
}